// Round 7
// baseline (116.987 us; speedup 1.0000x reference)
//
#include <hip/hip_runtime.h>

// ChamferLoss: B=4, C=3, N=M=8192 fp32.
// loss = 2 * mean_b( sum_n min_m ||q_n - r_m||^2 ), clamp >= 0.
// s(n,m) = q.r - 0.5*r^2 via v_mfma_f32_32x32x16_bf16, fp32 split as bf16
// hi+lo across K. Fragment bits identical to R10-R16 (verified absmax 0.0).
//
// ROUND 17: INSTRUMENTATION ROUND -- measure main's true cost in-harness.
// R16 answered: the 268MB ws poison fill (40.5us) is UNCONDITIONAL (ws
// untouched, fills unchanged) => ws is free. Fused in-wave conversion
// regressed +10.3us => R14's prep+main is the best structure; restored
// here byte-identical. Remaining unknown: how much of dur_us is main vs
// fixed harness overhead F (the old "main=17.5, F=13" split was circular,
// both from the previous session's K1). rocprof top-5 shows only 40us
// fills, so main is invisible. Probe: launch the SAME main kernel 2 extra
// times with out -> scratch float at ws+4MiB (identical work, output
// unaffected, graph-capturable). dur = R14_dur + 2*main_true.
//   dur ~110-116 => main ~18 (loop genuinely slow -> attack with 16x16x32
//                   low-VGPR variant next)
//   dur ~86-92   => main ~6  (F~24 harness floor -> we're at the roofline)

#define NPTS 8192
#define NB   4
#define WPB  8        // waves per block
#define BT   (WPB * 64)
#define CPW  32       // chunks per wave (32 refs each)

typedef float f32x16 __attribute__((ext_vector_type(16)));
typedef short bf16x8 __attribute__((ext_vector_type(8)));

static __device__ __forceinline__ unsigned int f2bf(float f) {
    unsigned int u = __float_as_uint(f);
    u += 0x7FFF + ((u >> 16) & 1);          // RNE
    return u >> 16;
}
static __device__ __forceinline__ float bf2f(unsigned int s) {
    return __uint_as_float(s << 16);
}

// ---- K0: one-time ref -> A-fragment conversion ----
__global__ __launch_bounds__(512) void chamfer_prep(
    const float* __restrict__ pc1w,      // refs [B,3,N]
    uint4* __restrict__ wsA,             // [B][256][64] uint4 = 1 MiB
    float* __restrict__ out)
{
    const int g = blockIdx.x * 512 + threadIdx.x;   // 0..32767, one ref each
    if (g == 0) out[0] = 0.0f;                      // K1 accumulates after
    const int b = g >> 13, i = g & (NPTS - 1);
    const float* refb = pc1w + b * 3 * NPTS;
    float x = refb[i], y = refb[NPTS + i], z = refb[2 * NPTS + i];
    unsigned xh = f2bf(x), yh = f2bf(y), zh = f2bf(z);
    unsigned xl = f2bf(x - bf2f(xh));
    unsigned yl = f2bf(y - bf2f(yh));
    unsigned zl = f2bf(z - bf2f(zh));
    float h = -0.5f * (x * x + y * y + z * z);
    unsigned hh = f2bf(h);
    unsigned hl = f2bf(h - bf2f(hh));
    const int c = i >> 5, l = i & 31;
    // A k0..7 = [xh,xl,xh,yh,yl,yh,zh,zl], k8..15 = [zh,hh,hl,0,...]
    uint4* dst = wsA + (((size_t)b * 256 + c) << 6);
    dst[l]      = make_uint4(xh | (xl << 16), xh | (yh << 16),
                             yl | (yh << 16), zh | (zl << 16));
    dst[32 + l] = make_uint4(zh | (hh << 16), hl, 0u, 0u);
}

static __device__ __forceinline__ bf16x8 make_bfrag(float x, float y, float z,
                                                    int lane)
{
    unsigned xh = f2bf(x), yh = f2bf(y), zh = f2bf(z);
    unsigned xl = f2bf(x - bf2f(xh));
    unsigned yl = f2bf(y - bf2f(yh));
    unsigned zl = f2bf(z - bf2f(zh));
    // B k0..7 = [xh,xh,xl,yh,yh,yl,zh,zh], k8..15 = [zl,1,1,0,...]
    uint4 bu = (lane < 32)
        ? make_uint4(xh | (xh << 16), xl | (yh << 16),
                     yh | (yl << 16), zh | (zh << 16))
        : make_uint4(zl | (0x3F80u << 16), 0x3F80u, 0u, 0u);
    return __builtin_bit_cast(bf16x8, bu);
}

static __device__ __forceinline__ void proc_chunk(
    uint4 av, bf16x8 bq0, bf16x8 bq1, const f32x16& zero,
    float& rma0, float& rma1, float& rma2, float& rma3,
    float& rmb0, float& rmb1, float& rmb2, float& rmb3)
{
    bf16x8 aa = __builtin_bit_cast(bf16x8, av);
    f32x16 d0 = __builtin_amdgcn_mfma_f32_32x32x16_bf16(aa, bq0, zero, 0, 0, 0);
    f32x16 d1 = __builtin_amdgcn_mfma_f32_32x32x16_bf16(aa, bq1, zero, 0, 0, 0);
    // each line is a 3-input max -> v_max3_f32
    rma0 = fmaxf(rma0, fmaxf(d0[0],  d0[1]));   // rows = refs
    rma0 = fmaxf(rma0, fmaxf(d0[2],  d0[3]));
    rma1 = fmaxf(rma1, fmaxf(d0[4],  d0[5]));
    rma1 = fmaxf(rma1, fmaxf(d0[6],  d0[7]));
    rma2 = fmaxf(rma2, fmaxf(d0[8],  d0[9]));
    rma2 = fmaxf(rma2, fmaxf(d0[10], d0[11]));
    rma3 = fmaxf(rma3, fmaxf(d0[12], d0[13]));
    rma3 = fmaxf(rma3, fmaxf(d0[14], d0[15]));
    rmb0 = fmaxf(rmb0, fmaxf(d1[0],  d1[1]));
    rmb0 = fmaxf(rmb0, fmaxf(d1[2],  d1[3]));
    rmb1 = fmaxf(rmb1, fmaxf(d1[4],  d1[5]));
    rmb1 = fmaxf(rmb1, fmaxf(d1[6],  d1[7]));
    rmb2 = fmaxf(rmb2, fmaxf(d1[8],  d1[9]));
    rmb2 = fmaxf(rmb2, fmaxf(d1[10], d1[11]));
    rmb3 = fmaxf(rmb3, fmaxf(d1[12], d1[13]));
    rmb3 = fmaxf(rmb3, fmaxf(d1[14], d1[15]));
}

// ---- K1: fused main kernel, modulo-scheduled 8-deep register pipeline ----
__global__ __launch_bounds__(BT, 4) void chamfer_main(
    const float* __restrict__ pc2,       // queries [B,3,N]
    const uint4* __restrict__ wsA,       // precomputed A-fragments
    float* __restrict__ out)
{
    __shared__ float red[WPB][64];       // cross-wave max partials (2 KB)
    const int tid  = threadIdx.x;
    const int wave = tid >> 6;
    const int lane = tid & 63;
    const int b    = blockIdx.y;
    const int qc0  = blockIdx.x * 2;     // 2 query chunks = 64 queries / block

    // per-lane query B-fragments (columns = lane&31 of q-chunks qc0, qc0+1)
    const float* qb = pc2 + b * 3 * NPTS;
    const int qn0 = qc0 * 32 + (lane & 31);
    const int qn1 = qn0 + 32;
    float x0 = qb[qn0], y0 = qb[NPTS + qn0], z0 = qb[2 * NPTS + qn0];
    float x1 = qb[qn1], y1 = qb[NPTS + qn1], z1 = qb[2 * NPTS + qn1];
    bf16x8 bq0 = make_bfrag(x0, y0, z0, lane);
    bf16x8 bq1 = make_bfrag(x1, y1, z1, lane);

    f32x16 zero;
#pragma unroll
    for (int i = 0; i < 16; ++i) zero[i] = 0.0f;

    float rma0 = -3e38f, rma1 = -3e38f, rma2 = -3e38f, rma3 = -3e38f;
    float rmb0 = -3e38f, rmb1 = -3e38f, rmb2 = -3e38f, rmb3 = -3e38f;

    // wave w owns 32 contiguous chunks (1024 refs); chunk c at s[c*64]
    const uint4* s = wsA + (((size_t)b * 256 + wave * CPW) << 6) + lane;

    // 8 rotating buffers; reload of each buffer issued right after its use
    uint4 p0 = s[0],       p1 = s[64],      p2 = s[128],     p3 = s[192];
    uint4 p4 = s[256],     p5 = s[320],     p6 = s[384],     p7 = s[448];
#pragma unroll 1
    for (int g = 0; g < CPW / 8; ++g) {
        // tail-group reloads run 8 chunks past range: stay inside 256 MiB
        // ws (harmless, never consumed)
        const uint4* nx = s + (g + 1) * 512;
        proc_chunk(p0, bq0, bq1, zero, rma0, rma1, rma2, rma3,
                   rmb0, rmb1, rmb2, rmb3);
        p0 = nx[0];
        proc_chunk(p1, bq0, bq1, zero, rma0, rma1, rma2, rma3,
                   rmb0, rmb1, rmb2, rmb3);
        p1 = nx[64];
        proc_chunk(p2, bq0, bq1, zero, rma0, rma1, rma2, rma3,
                   rmb0, rmb1, rmb2, rmb3);
        p2 = nx[128];
        proc_chunk(p3, bq0, bq1, zero, rma0, rma1, rma2, rma3,
                   rmb0, rmb1, rmb2, rmb3);
        p3 = nx[192];
        proc_chunk(p4, bq0, bq1, zero, rma0, rma1, rma2, rma3,
                   rmb0, rmb1, rmb2, rmb3);
        p4 = nx[256];
        proc_chunk(p5, bq0, bq1, zero, rma0, rma1, rma2, rma3,
                   rmb0, rmb1, rmb2, rmb3);
        p5 = nx[320];
        proc_chunk(p6, bq0, bq1, zero, rma0, rma1, rma2, rma3,
                   rmb0, rmb1, rmb2, rmb3);
        p6 = nx[384];
        proc_chunk(p7, bq0, bq1, zero, rma0, rma1, rma2, rma3,
                   rmb0, rmb1, rmb2, rmb3);
        p7 = nx[448];
    }

    float rma = fmaxf(fmaxf(rma0, rma1), fmaxf(rma2, rma3));
    float rmb = fmaxf(fmaxf(rmb0, rmb1), fmaxf(rmb2, rmb3));
    // lanes l and l^32 hold the two row-halves of the same query column
    rma = fmaxf(rma, __shfl_xor(rma, 32, 64));
    rmb = fmaxf(rmb, __shfl_xor(rmb, 32, 64));
    if (lane < 32) {
        red[wave][lane]      = rma;
        red[wave][32 + lane] = rmb;
    }
    __syncthreads();

    if (tid < 64) {                      // wave 0 finalizes 64 queries
        float smax = red[0][tid];
#pragma unroll
        for (int w = 1; w < WPB; ++w) smax = fmaxf(smax, red[w][tid]);
        const int n = qc0 * 32 + tid;
        float qx = qb[n], qy = qb[NPTS + n], qz = qb[2 * NPTS + n];
        float d = fmaxf(qx * qx + qy * qy + qz * qz - 2.0f * smax, 0.0f);
#pragma unroll
        for (int off = 32; off > 0; off >>= 1)
            d += __shfl_down(d, off, 64);
        if (tid == 0)
            atomicAdd(out, d * (2.0f / NB));     // 2 * mean over batches
    }
}

extern "C" void kernel_launch(void* const* d_in, const int* in_sizes, int n_in,
                              void* d_out, int out_size, void* d_ws, size_t ws_size,
                              hipStream_t stream) {
    const float* pc2  = (const float*)d_in[0];
    const float* pc1w = (const float*)d_in[1];
    float* out = (float*)d_out;
    uint4* wsA = (uint4*)d_ws;           // B*256*64*16 B = 1 MiB (+8 KB slack)
    // scratch accumulator for probe launches, far from wsA (at ws+4 MiB);
    // written by atomicAdd only, never read back.
    float* probe_out = (float*)((char*)d_ws + (4u << 20));

    chamfer_prep<<<NB * NPTS / 512, 512, 0, stream>>>(pc1w, wsA, out);
    dim3 g(128, NB);                     // 512 blocks = 2/CU, one round
    chamfer_main<<<g, BT, 0, stream>>>(pc2, wsA, out);
    // PROBE: two duplicate launches of the identical kernel, output to ws
    // scratch. dur_us excess over R14 (75.75) = 2x main's true cost.
    chamfer_main<<<g, BT, 0, stream>>>(pc2, wsA, probe_out);
    chamfer_main<<<g, BT, 0, stream>>>(pc2, wsA, probe_out);
}

// Round 8
// 76.395 us; speedup vs baseline: 1.5313x; 1.5313x over previous
//
#include <hip/hip_runtime.h>

// ChamferLoss: B=4, C=3, N=M=8192 fp32.
// loss = 2 * mean_b( sum_n min_m ||q_n - r_m||^2 ), clamp >= 0.
// s(n,m) = q.r - 0.5*r^2 via v_mfma_f32_32x32x16_bf16, fp32 split as bf16
// hi+lo across K. Fragment bits identical to R10-R17 (verified absmax 0.0).
//
// ROUND 18: non-temporal prep stores -- fix the memory CLASS of main's reads.
// R17 probe: main's true marginal cost = (116.99-75.75)/2 = 20.6us, steady
// state (probe launches 2,3 ran with warm clocks -> DVFS ruled out).
// Main's request volume = 4096 waves x 32 KB = 134 MB; 134MB/20.6us =
// 6.5 TB/s = the HBM-class per-CU service rate (~10 B/cyc/CU). L2-hit
// model says ~3-4us => the fragment reads are NOT being served by local
// L2. Cause: prep leaves fragment lines DIRTY in the writer XCD's L2
// (64 prep blocks scatter-write across all 8 XCDs); main's readers on
// other XCDs hit the non-coherent remote-dirty path at HBM-class rates
// for EVERY request. Explains R12/R13/R14 invariance (bandwidth-class
// wall, schedule-immune). Fix: __builtin_nontemporal_store in prep ->
// lines land CLEAN at memory side (L3); each XCD L2 then caches clean
// copies and serves at L2 rates. Everything else byte-identical to R14;
// probe launches removed.
//   theory right: dur 75.75 -> ~59-64 (main ~4-7)
//   theory wrong: dur ~75-77 -> next round halves request volume (QPW=4)

#define NPTS 8192
#define NB   4
#define WPB  8        // waves per block
#define BT   (WPB * 64)
#define CPW  32       // chunks per wave (32 refs each)

typedef float f32x16 __attribute__((ext_vector_type(16)));
typedef short bf16x8 __attribute__((ext_vector_type(8)));
typedef unsigned int u32x4 __attribute__((ext_vector_type(4)));

static __device__ __forceinline__ unsigned int f2bf(float f) {
    unsigned int u = __float_as_uint(f);
    u += 0x7FFF + ((u >> 16) & 1);          // RNE
    return u >> 16;
}
static __device__ __forceinline__ float bf2f(unsigned int s) {
    return __uint_as_float(s << 16);
}

// ---- K0: one-time ref -> A-fragment conversion (non-temporal stores) ----
__global__ __launch_bounds__(512) void chamfer_prep(
    const float* __restrict__ pc1w,      // refs [B,3,N]
    uint4* __restrict__ wsA,             // [B][256][64] uint4 = 1 MiB
    float* __restrict__ out)
{
    const int g = blockIdx.x * 512 + threadIdx.x;   // 0..32767, one ref each
    if (g == 0) out[0] = 0.0f;                      // K1 accumulates after
    const int b = g >> 13, i = g & (NPTS - 1);
    const float* refb = pc1w + b * 3 * NPTS;
    float x = refb[i], y = refb[NPTS + i], z = refb[2 * NPTS + i];
    unsigned xh = f2bf(x), yh = f2bf(y), zh = f2bf(z);
    unsigned xl = f2bf(x - bf2f(xh));
    unsigned yl = f2bf(y - bf2f(yh));
    unsigned zl = f2bf(z - bf2f(zh));
    float h = -0.5f * (x * x + y * y + z * z);
    unsigned hh = f2bf(h);
    unsigned hl = f2bf(h - bf2f(hh));
    const int c = i >> 5, l = i & 31;
    // A k0..7 = [xh,xl,xh,yh,yl,yh,zh,zl], k8..15 = [zh,hh,hl,0,...]
    uint4* dst = wsA + (((size_t)b * 256 + c) << 6);
    // non-temporal: no-allocate in writer L2 -> lines land clean at the
    // memory side; reader XCDs can cache them locally (the whole point).
    u32x4 w0 = { xh | (xl << 16), xh | (yh << 16),
                 yl | (yh << 16), zh | (zl << 16) };
    u32x4 w1 = { zh | (hh << 16), hl, 0u, 0u };
    __builtin_nontemporal_store(w0, (u32x4*)(dst + l));
    __builtin_nontemporal_store(w1, (u32x4*)(dst + 32 + l));
}

static __device__ __forceinline__ bf16x8 make_bfrag(float x, float y, float z,
                                                    int lane)
{
    unsigned xh = f2bf(x), yh = f2bf(y), zh = f2bf(z);
    unsigned xl = f2bf(x - bf2f(xh));
    unsigned yl = f2bf(y - bf2f(yh));
    unsigned zl = f2bf(z - bf2f(zh));
    // B k0..7 = [xh,xh,xl,yh,yh,yl,zh,zh], k8..15 = [zl,1,1,0,...]
    uint4 bu = (lane < 32)
        ? make_uint4(xh | (xh << 16), xl | (yh << 16),
                     yh | (yl << 16), zh | (zh << 16))
        : make_uint4(zl | (0x3F80u << 16), 0x3F80u, 0u, 0u);
    return __builtin_bit_cast(bf16x8, bu);
}

static __device__ __forceinline__ void proc_chunk(
    uint4 av, bf16x8 bq0, bf16x8 bq1, const f32x16& zero,
    float& rma0, float& rma1, float& rma2, float& rma3,
    float& rmb0, float& rmb1, float& rmb2, float& rmb3)
{
    bf16x8 aa = __builtin_bit_cast(bf16x8, av);
    f32x16 d0 = __builtin_amdgcn_mfma_f32_32x32x16_bf16(aa, bq0, zero, 0, 0, 0);
    f32x16 d1 = __builtin_amdgcn_mfma_f32_32x32x16_bf16(aa, bq1, zero, 0, 0, 0);
    // each line is a 3-input max -> v_max3_f32
    rma0 = fmaxf(rma0, fmaxf(d0[0],  d0[1]));   // rows = refs
    rma0 = fmaxf(rma0, fmaxf(d0[2],  d0[3]));
    rma1 = fmaxf(rma1, fmaxf(d0[4],  d0[5]));
    rma1 = fmaxf(rma1, fmaxf(d0[6],  d0[7]));
    rma2 = fmaxf(rma2, fmaxf(d0[8],  d0[9]));
    rma2 = fmaxf(rma2, fmaxf(d0[10], d0[11]));
    rma3 = fmaxf(rma3, fmaxf(d0[12], d0[13]));
    rma3 = fmaxf(rma3, fmaxf(d0[14], d0[15]));
    rmb0 = fmaxf(rmb0, fmaxf(d1[0],  d1[1]));
    rmb0 = fmaxf(rmb0, fmaxf(d1[2],  d1[3]));
    rmb1 = fmaxf(rmb1, fmaxf(d1[4],  d1[5]));
    rmb1 = fmaxf(rmb1, fmaxf(d1[6],  d1[7]));
    rmb2 = fmaxf(rmb2, fmaxf(d1[8],  d1[9]));
    rmb2 = fmaxf(rmb2, fmaxf(d1[10], d1[11]));
    rmb3 = fmaxf(rmb3, fmaxf(d1[12], d1[13]));
    rmb3 = fmaxf(rmb3, fmaxf(d1[14], d1[15]));
}

// ---- K1: fused main kernel, modulo-scheduled 8-deep register pipeline ----
__global__ __launch_bounds__(BT, 4) void chamfer_main(
    const float* __restrict__ pc2,       // queries [B,3,N]
    const uint4* __restrict__ wsA,       // precomputed A-fragments
    float* __restrict__ out)
{
    __shared__ float red[WPB][64];       // cross-wave max partials (2 KB)
    const int tid  = threadIdx.x;
    const int wave = tid >> 6;
    const int lane = tid & 63;
    const int b    = blockIdx.y;
    const int qc0  = blockIdx.x * 2;     // 2 query chunks = 64 queries / block

    // per-lane query B-fragments (columns = lane&31 of q-chunks qc0, qc0+1)
    const float* qb = pc2 + b * 3 * NPTS;
    const int qn0 = qc0 * 32 + (lane & 31);
    const int qn1 = qn0 + 32;
    float x0 = qb[qn0], y0 = qb[NPTS + qn0], z0 = qb[2 * NPTS + qn0];
    float x1 = qb[qn1], y1 = qb[NPTS + qn1], z1 = qb[2 * NPTS + qn1];
    bf16x8 bq0 = make_bfrag(x0, y0, z0, lane);
    bf16x8 bq1 = make_bfrag(x1, y1, z1, lane);

    f32x16 zero;
#pragma unroll
    for (int i = 0; i < 16; ++i) zero[i] = 0.0f;

    float rma0 = -3e38f, rma1 = -3e38f, rma2 = -3e38f, rma3 = -3e38f;
    float rmb0 = -3e38f, rmb1 = -3e38f, rmb2 = -3e38f, rmb3 = -3e38f;

    // wave w owns 32 contiguous chunks (1024 refs); chunk c at s[c*64]
    const uint4* s = wsA + (((size_t)b * 256 + wave * CPW) << 6) + lane;

    // 8 rotating buffers; reload of each buffer issued right after its use
    uint4 p0 = s[0],       p1 = s[64],      p2 = s[128],     p3 = s[192];
    uint4 p4 = s[256],     p5 = s[320],     p6 = s[384],     p7 = s[448];
#pragma unroll 1
    for (int g = 0; g < CPW / 8; ++g) {
        // tail-group reloads run 8 chunks past range: stay inside 256 MiB
        // ws (harmless, never consumed)
        const uint4* nx = s + (g + 1) * 512;
        proc_chunk(p0, bq0, bq1, zero, rma0, rma1, rma2, rma3,
                   rmb0, rmb1, rmb2, rmb3);
        p0 = nx[0];
        proc_chunk(p1, bq0, bq1, zero, rma0, rma1, rma2, rma3,
                   rmb0, rmb1, rmb2, rmb3);
        p1 = nx[64];
        proc_chunk(p2, bq0, bq1, zero, rma0, rma1, rma2, rma3,
                   rmb0, rmb1, rmb2, rmb3);
        p2 = nx[128];
        proc_chunk(p3, bq0, bq1, zero, rma0, rma1, rma2, rma3,
                   rmb0, rmb1, rmb2, rmb3);
        p3 = nx[192];
        proc_chunk(p4, bq0, bq1, zero, rma0, rma1, rma2, rma3,
                   rmb0, rmb1, rmb2, rmb3);
        p4 = nx[256];
        proc_chunk(p5, bq0, bq1, zero, rma0, rma1, rma2, rma3,
                   rmb0, rmb1, rmb2, rmb3);
        p5 = nx[320];
        proc_chunk(p6, bq0, bq1, zero, rma0, rma1, rma2, rma3,
                   rmb0, rmb1, rmb2, rmb3);
        p6 = nx[384];
        proc_chunk(p7, bq0, bq1, zero, rma0, rma1, rma2, rma3,
                   rmb0, rmb1, rmb2, rmb3);
        p7 = nx[448];
    }

    float rma = fmaxf(fmaxf(rma0, rma1), fmaxf(rma2, rma3));
    float rmb = fmaxf(fmaxf(rmb0, rmb1), fmaxf(rmb2, rmb3));
    // lanes l and l^32 hold the two row-halves of the same query column
    rma = fmaxf(rma, __shfl_xor(rma, 32, 64));
    rmb = fmaxf(rmb, __shfl_xor(rmb, 32, 64));
    if (lane < 32) {
        red[wave][lane]      = rma;
        red[wave][32 + lane] = rmb;
    }
    __syncthreads();

    if (tid < 64) {                      // wave 0 finalizes 64 queries
        float smax = red[0][tid];
#pragma unroll
        for (int w = 1; w < WPB; ++w) smax = fmaxf(smax, red[w][tid]);
        const int n = qc0 * 32 + tid;
        float qx = qb[n], qy = qb[NPTS + n], qz = qb[2 * NPTS + n];
        float d = fmaxf(qx * qx + qy * qy + qz * qz - 2.0f * smax, 0.0f);
#pragma unroll
        for (int off = 32; off > 0; off >>= 1)
            d += __shfl_down(d, off, 64);
        if (tid == 0)
            atomicAdd(out, d * (2.0f / NB));     // 2 * mean over batches
    }
}

extern "C" void kernel_launch(void* const* d_in, const int* in_sizes, int n_in,
                              void* d_out, int out_size, void* d_ws, size_t ws_size,
                              hipStream_t stream) {
    const float* pc2  = (const float*)d_in[0];
    const float* pc1w = (const float*)d_in[1];
    float* out = (float*)d_out;
    uint4* wsA = (uint4*)d_ws;           // B*256*64*16 B = 1 MiB (+8 KB slack)

    chamfer_prep<<<NB * NPTS / 512, 512, 0, stream>>>(pc1w, wsA, out);
    dim3 g(128, NB);                     // 512 blocks = 2/CU, one round
    chamfer_main<<<g, BT, 0, stream>>>(pc2, wsA, out);
}

// Round 9
// 73.608 us; speedup vs baseline: 1.5893x; 1.0379x over previous
//
#include <hip/hip_runtime.h>

// ChamferLoss: B=4, C=3, N=M=8192 fp32.
// loss = 2 * mean_b( sum_n min_m ||q_n - r_m||^2 ), clamp >= 0.
// s(n,m) = q.r - 0.5*r^2 via v_mfma_f32_32x32x16_bf16, fp32 split as bf16
// hi+lo across K. Fragment bits identical to R10-R18 (verified absmax 0.0).
//
// ROUND 19: intra-block A-sharing -- cut load volume 15x.
// Evidence chain: R17 probe = main 20.6us; request volume 134 MB at
// ~10 B/cyc/CU (HBM-class) regardless of schedule (R12/13/14) or store
// class (R18 nontemporal: no change). Service rate is immovable => cut
// volume. Old structure: each wave reads its OWN 32KB of fragments (zero
// block-level reuse). New: block = 16 q-chunks x 1024 refs; 8 waves SHARE
// one 32KB A-fragment LDS image (converted in-block from raw pc1w, each
// thread converts 2 refs ONCE -- unlike R16's per-consumption convert),
// each wave owns 2 q-chunks. Global traffic ~18KB/block (~9MB total,
// clean host-written, L2-native). Prep kernel + ws fragment buffer GONE.
// Per-query max over the 8 ref ranges -> ws partials (1 MiB, free per
// R16) + R10's verified reduce kernel. One barrier per block; no loop
// barriers; contiguous conflict-free ds_read_b128.
//   dur 76.4 -> ~60-64 expected (main ~4-5, VALU-bound);
//   if ~74-77: harness-fixed floor dominates -> declare roofline.

#define NPTS 8192
#define NB   4
#define RRN  8        // ref ranges (1024 refs each)
#define QGN  16       // q-chunk groups per batch (16 q-chunks each)
#define BT   512

typedef float f32x16 __attribute__((ext_vector_type(16)));
typedef short bf16x8 __attribute__((ext_vector_type(8)));

static __device__ __forceinline__ unsigned int f2bf(float f) {
    unsigned int u = __float_as_uint(f);
    u += 0x7FFF + ((u >> 16) & 1);          // RNE
    return u >> 16;
}
static __device__ __forceinline__ float bf2f(unsigned int s) {
    return __uint_as_float(s << 16);
}

static __device__ __forceinline__ bf16x8 make_bfrag(float x, float y, float z,
                                                    int lane)
{
    unsigned xh = f2bf(x), yh = f2bf(y), zh = f2bf(z);
    unsigned xl = f2bf(x - bf2f(xh));
    unsigned yl = f2bf(y - bf2f(yh));
    unsigned zl = f2bf(z - bf2f(zh));
    // B k0..7 = [xh,xh,xl,yh,yh,yl,zh,zh], k8..15 = [zl,1,1,0,...]
    uint4 bu = (lane < 32)
        ? make_uint4(xh | (xh << 16), xl | (yh << 16),
                     yh | (yl << 16), zh | (zh << 16))
        : make_uint4(zl | (0x3F80u << 16), 0x3F80u, 0u, 0u);
    return __builtin_bit_cast(bf16x8, bu);
}

static __device__ __forceinline__ void proc_chunk(
    uint4 av, bf16x8 bq0, bf16x8 bq1, const f32x16& zero,
    float& rma0, float& rma1, float& rma2, float& rma3,
    float& rmb0, float& rmb1, float& rmb2, float& rmb3)
{
    bf16x8 aa = __builtin_bit_cast(bf16x8, av);
    f32x16 d0 = __builtin_amdgcn_mfma_f32_32x32x16_bf16(aa, bq0, zero, 0, 0, 0);
    f32x16 d1 = __builtin_amdgcn_mfma_f32_32x32x16_bf16(aa, bq1, zero, 0, 0, 0);
    // each line is a 3-input max -> v_max3_f32
    rma0 = fmaxf(rma0, fmaxf(d0[0],  d0[1]));   // rows = refs
    rma0 = fmaxf(rma0, fmaxf(d0[2],  d0[3]));
    rma1 = fmaxf(rma1, fmaxf(d0[4],  d0[5]));
    rma1 = fmaxf(rma1, fmaxf(d0[6],  d0[7]));
    rma2 = fmaxf(rma2, fmaxf(d0[8],  d0[9]));
    rma2 = fmaxf(rma2, fmaxf(d0[10], d0[11]));
    rma3 = fmaxf(rma3, fmaxf(d0[12], d0[13]));
    rma3 = fmaxf(rma3, fmaxf(d0[14], d0[15]));
    rmb0 = fmaxf(rmb0, fmaxf(d1[0],  d1[1]));
    rmb0 = fmaxf(rmb0, fmaxf(d1[2],  d1[3]));
    rmb1 = fmaxf(rmb1, fmaxf(d1[4],  d1[5]));
    rmb1 = fmaxf(rmb1, fmaxf(d1[6],  d1[7]));
    rmb2 = fmaxf(rmb2, fmaxf(d1[8],  d1[9]));
    rmb2 = fmaxf(rmb2, fmaxf(d1[10], d1[11]));
    rmb3 = fmaxf(rmb3, fmaxf(d1[12], d1[13]));
    rmb3 = fmaxf(rmb3, fmaxf(d1[14], d1[15]));
}

// ---- K1: shared-A main kernel ----
// grid (QGN, RRN, NB) = (16,8,4) = 512 blocks = 2/CU, one round.
__global__ __launch_bounds__(BT, 4) void chamfer_main(
    const float* __restrict__ pc2,       // queries [B,3,N]
    const float* __restrict__ pc1w,      // refs    [B,3,N]
    float* __restrict__ partial,         // [B][RRN][NPTS] in ws (1 MiB)
    float* __restrict__ out)
{
    __shared__ uint4 slds[32 * 64];      // 32 KB: A-fragments for 1024 refs
    const int tid  = threadIdx.x;
    const int wave = tid >> 6;
    const int lane = tid & 63;
    const int b    = blockIdx.z;
    const int rr   = blockIdx.y;
    const int qg   = blockIdx.x;

    // zero the accumulator for K2's atomics (K2 is a later dispatch ->
    // stream-ordered; pattern verified in R10)
    if (qg == 0 && rr == 0 && b == 0 && tid == 0) out[0] = 0.0f;

    // stage + convert this range's 1024 refs into A-fragment layout
    // (bit-identical to R11's verified staging conversion)
    const float* refb = pc1w + b * 3 * NPTS + rr * 1024;
#pragma unroll
    for (int j = 0; j < 2; ++j) {
        int i = tid + j * BT;            // 0..1023, coalesced
        float x = refb[i], y = refb[NPTS + i], z = refb[2 * NPTS + i];
        unsigned xh = f2bf(x), yh = f2bf(y), zh = f2bf(z);
        unsigned xl = f2bf(x - bf2f(xh));
        unsigned yl = f2bf(y - bf2f(yh));
        unsigned zl = f2bf(z - bf2f(zh));
        float h = -0.5f * (x * x + y * y + z * z);
        unsigned hh = f2bf(h);
        unsigned hl = f2bf(h - bf2f(hh));
        int c = i >> 5, l32 = i & 31;
        // A k0..7 = [xh,xl,xh,yh,yl,yh,zh,zl], k8..15 = [zh,hh,hl,0,...]
        slds[c * 64 + l32] =
            make_uint4(xh | (xl << 16), xh | (yh << 16),
                       yl | (yh << 16), zh | (zl << 16));
        slds[c * 64 + 32 + l32] = make_uint4(zh | (hh << 16), hl, 0u, 0u);
    }

    // this wave's 2 query chunks (of the block's 16)
    const int qc0 = qg * 16 + wave * 2;
    const float* qb = pc2 + b * 3 * NPTS;
    const int qn0 = qc0 * 32 + (lane & 31);
    const int qn1 = qn0 + 32;
    float x0 = qb[qn0], y0 = qb[NPTS + qn0], z0 = qb[2 * NPTS + qn0];
    float x1 = qb[qn1], y1 = qb[NPTS + qn1], z1 = qb[2 * NPTS + qn1];
    bf16x8 bq0 = make_bfrag(x0, y0, z0, lane);
    bf16x8 bq1 = make_bfrag(x1, y1, z1, lane);

    f32x16 zero;
#pragma unroll
    for (int i = 0; i < 16; ++i) zero[i] = 0.0f;

    float rma0 = -3e38f, rma1 = -3e38f, rma2 = -3e38f, rma3 = -3e38f;
    float rmb0 = -3e38f, rmb1 = -3e38f, rmb2 = -3e38f, rmb3 = -3e38f;

    __syncthreads();                     // LDS image complete

    // all 8 waves share the same 32 chunks; ds_read 1 ahead
    uint4 av = slds[lane];
#pragma unroll 4
    for (int c = 0; c < 32; ++c) {
        uint4 acur = av;
        if (c + 1 < 32)
            av = slds[(c + 1) * 64 + lane];
        proc_chunk(acur, bq0, bq1, zero, rma0, rma1, rma2, rma3,
                   rmb0, rmb1, rmb2, rmb3);
    }

    float rma = fmaxf(fmaxf(rma0, rma1), fmaxf(rma2, rma3));
    float rmb = fmaxf(fmaxf(rmb0, rmb1), fmaxf(rmb2, rmb3));
    // lanes l and l^32 hold the two row-halves of the same query column
    rma = fmaxf(rma, __shfl_xor(rma, 32, 64));
    rmb = fmaxf(rmb, __shfl_xor(rmb, 32, 64));
    float* pb = partial + ((size_t)b * RRN + rr) * NPTS + qc0 * 32;
    if (lane < 32) {
        pb[lane]      = rma;
        pb[32 + lane] = rmb;
    }
}

// ---- K2: finalize (verified R10 structure) ----
__global__ __launch_bounds__(512) void chamfer_reduce(
    const float* __restrict__ pc2,
    const float* __restrict__ partial,
    float* __restrict__ out)
{
    const int g = blockIdx.x * 512 + threadIdx.x;   // query id
    const int b = g >> 13, n = g & 8191;
    float smax = -3e38f;
#pragma unroll
    for (int c = 0; c < RRN; ++c)
        smax = fmaxf(smax, partial[((size_t)b * RRN + c) * NPTS + n]);

    const float* qb = pc2 + b * 3 * NPTS;
    float qx = qb[n], qy = qb[NPTS + n], qz = qb[2 * NPTS + n];
    float q2 = qx * qx + qy * qy + qz * qz;
    float d = fmaxf(q2 - 2.0f * smax, 0.0f);

#pragma unroll
    for (int off = 32; off > 0; off >>= 1)
        d += __shfl_down(d, off, 64);

    __shared__ float wsum[8];
    const int lane = threadIdx.x & 63;
    const int wid  = threadIdx.x >> 6;
    if (lane == 0) wsum[wid] = d;
    __syncthreads();
    if (threadIdx.x == 0) {
        float s = 0.0f;
#pragma unroll
        for (int w = 0; w < 8; ++w) s += wsum[w];
        atomicAdd(out, s * (2.0f / NB));   // 2 * mean over batches
    }
}

extern "C" void kernel_launch(void* const* d_in, const int* in_sizes, int n_in,
                              void* d_out, int out_size, void* d_ws, size_t ws_size,
                              hipStream_t stream) {
    const float* pc2  = (const float*)d_in[0];
    const float* pc1w = (const float*)d_in[1];
    float* out = (float*)d_out;
    float* partial = (float*)d_ws;       // B * RRN * NPTS * 4 = 1 MiB

    dim3 g1(QGN, RRN, NB);               // (16,8,4) = 512 blocks = 2/CU
    chamfer_main<<<g1, BT, 0, stream>>>(pc2, pc1w, partial, out);
    chamfer_reduce<<<NB * NPTS / 512, 512, 0, stream>>>(pc2, partial, out);
}